// Round 2
// baseline (683.551 us; speedup 1.0000x reference)
//
#include <hip/hip_runtime.h>
#include <hip/hip_bf16.h>

#define B_  4
#define T_  2048
#define D_  2048
#define H_  16
#define DH_ 128
#define KG  2048   // GEMM K (= D_)

typedef __attribute__((ext_vector_type(4))) float f32x4;
typedef __attribute__((ext_vector_type(8))) short short8;
typedef __attribute__((ext_vector_type(4))) _Float16 half4;

__device__ __forceinline__ ushort f2bf(float f) {
    unsigned int u = __builtin_bit_cast(unsigned int, f);
    u += 0x7fffu + ((u >> 16) & 1u);   // RNE
    return (ushort)(u >> 16);
}
__device__ __forceinline__ ushort f2h(float f) {
    return (ushort)(__builtin_bit_cast(unsigned int, __builtin_amdgcn_cvt_pkrtz(f, f)) & 0xffffu);
}

// async global -> LDS, 16B per lane. LDS dst must be wave-uniform base + lane*16.
__device__ __forceinline__ void glds16(const void* g, void* l) {
    __builtin_amdgcn_global_load_lds(
        (const __attribute__((address_space(1))) unsigned int*)g,
        (__attribute__((address_space(3))) unsigned int*)l, 16, 0, 0);
}

// ---------------------------------------------------------------- cast x -> bf16
__global__ void cast_f32_bf16(const float* __restrict__ x, ushort* __restrict__ xb, int n) {
    int i = (blockIdx.x * 256 + threadIdx.x) * 4;
    if (i < n) {
        float4 v = *(const float4*)(x + i);
        ushort4 o;
        o.x = f2bf(v.x); o.y = f2bf(v.y); o.z = f2bf(v.z); o.w = f2bf(v.w);
        *(ushort4*)(xb + i) = o;
    }
}

// ------------------------------------------------- W [k][n] fp32 -> Wt [n][k] bf16
__global__ void transpose_cast(const float* __restrict__ W, ushort* __restrict__ Wt) {
    __shared__ float tile[32][33];
    int tx = threadIdx.x, ty = threadIdx.y;           // 32 x 8
    int n0 = blockIdx.x * 32, k0 = blockIdx.y * 32;
#pragma unroll
    for (int i = 0; i < 4; i++)
        tile[ty + i * 8][tx] = W[(size_t)(k0 + ty + i * 8) * D_ + n0 + tx];
    __syncthreads();
#pragma unroll
    for (int i = 0; i < 4; i++)
        Wt[(size_t)(n0 + ty + i * 8) * D_ + k0 + tx] = f2bf(tile[tx][ty + i * 8]);
}

// ================================================================ 256x256 8-phase GEMM core
// 512 threads = 8 waves (2M x 4N). BK=64. LDS 128KiB: A[2 dbuf][2 region(qm)][128][64]bf16,
// B at +64KiB same shape (region qn). 16B-chunk swizzle ch^=(row&7) applied to the global
// SOURCE of global_load_lds (LDS linear) and to ds_read addrs.
// Register discipline (R1 fix): single aF[4][2]+bF[2][2] frag set (48 VGPR); B(qn0) is
// RELOADED from LDS at P4/P8 instead of held across phases.  Region ledger (verified):
//   reads:  A00@P1  B00@P1,P4  B01@P2  A01@P3  | A10@P5  B10@P5,P8  B11@P6  A11@P7
//   stages: P1:{A11,B10}(t1) P2:B11(t1) P3:A00(t2) P4:A01(t2) P5:B00(t2) P6:B01(t2) P7:A10(t3)
//   every stage lands in a region past its last read (barrier-separated).
//   vmcnt(4)@P4 retires {prevP5,prevP6,prevP7,P1,P2} -> covers P5/P6/P7 reads.
//   vmcnt(2)@P8 retires {P3,P4,P5,P6} -> covers next P1/P2/P3 reads.  Never 0 in loop.
// Tail stages clamp kt->31; they land only in dead regions (VM0 drains before epilogue).

#define LDS_A(d, qm, AF)                                                                   \
  { _Pragma("unroll") for (int mt = 0; mt < 4; ++mt) {                                     \
      AF[mt][0] = __builtin_bit_cast(short8,                                               \
          *(const uint4*)(smem + aAddr0 + (((d)*2 + (qm)) << 14) + mt*2048));              \
      AF[mt][1] = __builtin_bit_cast(short8,                                               \
          *(const uint4*)(smem + aAddr1 + (((d)*2 + (qm)) << 14) + mt*2048));              \
    } }

#define LDS_B(d, qn, BF)                                                                   \
  { _Pragma("unroll") for (int nt = 0; nt < 2; ++nt) {                                     \
      BF[nt][0] = __builtin_bit_cast(short8,                                               \
          *(const uint4*)(smem + bAddr0 + (((d)*2 + (qn)) << 14) + nt*2048));              \
      BF[nt][1] = __builtin_bit_cast(short8,                                               \
          *(const uint4*)(smem + bAddr1 + (((d)*2 + (qn)) << 14) + nt*2048));              \
    } }

#define STAGE_A(d, qm, kt)                                                                 \
  { const ushort* s_ = aSrc + (size_t)(qm) * (64 * KG) + (size_t)(kt) * 64;                \
    char* l_ = ldsT + (((d)*2 + (qm)) << 14);                                              \
    glds16(s_, l_);                                                                        \
    glds16(s_ + (size_t)128 * KG, l_ + 8192); }

#define STAGE_B(d, qn, kt)                                                                 \
  { const ushort* s_ = bSrc + (size_t)(qn) * (32 * KG) + (size_t)(kt) * 64;                \
    char* l_ = ldsT + 65536 + (((d)*2 + (qn)) << 14);                                      \
    glds16(s_, l_);                                                                        \
    glds16(s_ + (size_t)128 * KG, l_ + 8192); }

#define MFMA16(QM, QN, AF, BF)                                                             \
  __builtin_amdgcn_s_setprio(1);                                                           \
  _Pragma("unroll") for (int mt = 0; mt < 4; ++mt)                                         \
    _Pragma("unroll") for (int nt = 0; nt < 2; ++nt)                                       \
      _Pragma("unroll") for (int kk = 0; kk < 2; ++kk)                                     \
        acc[(QM)*4 + mt][(QN)*2 + nt] = __builtin_amdgcn_mfma_f32_16x16x32_bf16(           \
            AF[mt][kk], BF[nt][kk], acc[(QM)*4 + mt][(QN)*2 + nt], 0, 0, 0);               \
  __builtin_amdgcn_s_setprio(0);

#define BAR1_LGKM  __builtin_amdgcn_s_barrier();                                           \
                   asm volatile("s_waitcnt lgkmcnt(0)" ::: "memory");
#define BAR2       __builtin_amdgcn_s_barrier();
#define VM4        asm volatile("s_waitcnt vmcnt(4)" ::: "memory");
#define VM2        asm volatile("s_waitcnt vmcnt(2)" ::: "memory");
#define VM0        asm volatile("s_waitcnt vmcnt(0)" ::: "memory");

#define GEMM256_PRE                                                                        \
    const int lane = tid & 63, w = tid >> 6;                                               \
    const int l15 = lane & 15, quad = lane >> 4;                                           \
    const int wm = w & 1, wn = w >> 1;                                                     \
    const int irow = tid >> 3;                                                             \
    const int chl  = (tid & 7) ^ (irow & 7);                                               \
    const ushort* aSrc = Ap + (size_t)(row0 + irow) * KG + chl * 8;                        \
    const ushort* bSrc = Bp + (size_t)(col0 + ((irow >> 5) << 6) + (irow & 31)) * KG + chl * 8; \
    char* ldsT = smem + tid * 16;                                                          \
    const int sw0 = (quad ^ (l15 & 7)) << 4;                                               \
    const int sw1 = ((4 + quad) ^ (l15 & 7)) << 4;                                         \
    const int aRow = (wm * 64 + l15) * 128;                                                \
    const int bRow = (wn * 32 + l15) * 128;                                                \
    const int aAddr0 = aRow + sw0, aAddr1 = aRow + sw1;                                    \
    const int bAddr0 = 65536 + bRow + sw0, bAddr1 = 65536 + bRow + sw1;

#define GEMM256_MAIN_LOOP                                                                  \
    f32x4 acc[8][4] = {};                                                                  \
    short8 aF[4][2], bF[2][2];                                                             \
    STAGE_A(0, 0, 0); STAGE_B(0, 0, 0); STAGE_A(0, 1, 0); STAGE_B(0, 1, 0);                \
    STAGE_A(1, 0, 1);                                                                      \
    VM2; __builtin_amdgcn_s_barrier();                                                     \
    _Pragma("unroll 1")                                                                    \
    for (int j = 0; j < 16; ++j) {                                                         \
        const int t1 = 2*j + 1;                                                            \
        const int t2 = (2*j + 2 < 32) ? 2*j + 2 : 31;                                      \
        const int t3 = (2*j + 3 < 32) ? 2*j + 3 : 31;                                      \
        /* P1 */ LDS_A(0, 0, aF); LDS_B(0, 0, bF);                                         \
                 STAGE_A(1, 1, t1); STAGE_B(1, 0, t1);                                     \
                 BAR1_LGKM; MFMA16(0, 0, aF, bF); BAR2;                                    \
        /* P2 */ LDS_B(0, 1, bF); STAGE_B(1, 1, t1);                                       \
                 BAR1_LGKM; MFMA16(0, 1, aF, bF); BAR2;                                    \
        /* P3 */ LDS_A(0, 1, aF); STAGE_A(0, 0, t2);                                       \
                 BAR1_LGKM; MFMA16(1, 1, aF, bF); BAR2;                                    \
        /* P4 */ LDS_B(0, 0, bF); STAGE_A(0, 1, t2);                                       \
                 BAR1_LGKM; MFMA16(1, 0, aF, bF); VM4; BAR2;                               \
        /* P5 */ LDS_A(1, 0, aF); LDS_B(1, 0, bF); STAGE_B(0, 0, t2);                      \
                 BAR1_LGKM; MFMA16(0, 0, aF, bF); BAR2;                                    \
        /* P6 */ LDS_B(1, 1, bF); STAGE_B(0, 1, t2);                                       \
                 BAR1_LGKM; MFMA16(0, 1, aF, bF); BAR2;                                    \
        /* P7 */ LDS_A(1, 1, aF); STAGE_A(1, 0, t3);                                       \
                 BAR1_LGKM; MFMA16(1, 1, aF, bF); BAR2;                                    \
        /* P8 */ LDS_B(1, 0, bF);                                                          \
                 BAR1_LGKM; MFMA16(1, 0, aF, bF); VM2; BAR2;                               \
    }                                                                                      \
    VM0; __builtin_amdgcn_s_barrier();

// ---------------------------------------------------------------- merged QKV GEMM (256^2)
// grid (24, 32): sel = bx>>3 picks {Q,K,V}; V path emits f16 [B,H,DH,T].
__global__ __launch_bounds__(512, 2) void gemm_qkv256(
    const ushort* __restrict__ A,
    const ushort* __restrict__ Wq, const ushort* __restrict__ Wk, const ushort* __restrict__ Wv,
    const float* __restrict__ bq, const float* __restrict__ bk, const float* __restrict__ bv,
    ushort* __restrict__ Qb, ushort* __restrict__ Kb, ushort* __restrict__ Vtb,
    float qscale)
{
    extern __shared__ char smem[];
    const int tid = threadIdx.x;

    // bijective XCD swizzle (768 % 8 == 0): XCD x gets logical ids [x*96, x*96+96)
    int id = blockIdx.y * 24 + blockIdx.x;
    id = (id & 7) * 96 + (id >> 3);
    const int bx = id % 24, by = id / 24;

    const int sel  = bx >> 3;                    // 0=Q 1=K 2=V
    const int row0 = by * 256, col0 = (bx & 7) * 256;
    const ushort* Ap = A;
    const ushort* Bp = (sel == 0) ? Wq : (sel == 1) ? Wk : Wv;
    const float* bias = (sel == 0) ? bq : (sel == 1) ? bk : bv;
    const float oscale = (sel == 0) ? qscale : 1.0f;

    GEMM256_PRE
    GEMM256_MAIN_LOOP

    if (sel < 2) {
        ushort* Cout = sel ? Kb : Qb;
#pragma unroll
        for (int ntg = 0; ntg < 4; ++ntg) {
            int col = col0 + wn * 64 + ntg * 16 + l15;
            float bb = bias[col];
#pragma unroll
            for (int mtg = 0; mtg < 8; ++mtg) {
                int rowb = row0 + wm * 128 + mtg * 16 + quad * 4;
#pragma unroll
                for (int r = 0; r < 4; ++r)
                    Cout[(size_t)(rowb + r) * D_ + col] = f2bf((acc[mtg][ntg][r] + bb) * oscale);
            }
        }
    } else {
        // V path: per-wave transpose (two 32-dh rounds) -> f16 [B,H,DH,T]
        const int b = row0 >> 11, t0 = (row0 & (T_ - 1)) + wm * 128;
        const int h = (col0 + wn * 64) >> 7;
        ushort* eT = (ushort*)smem + w * (32 * 136);   // [32 dh][136 t-pad], wave-private
#pragma unroll 1
        for (int rnd = 0; rnd < 2; ++rnd) {
#pragma unroll
            for (int ni = 0; ni < 2; ++ni) {
                int ntg = rnd * 2 + ni;
                int col = col0 + wn * 64 + ntg * 16 + l15;
                float bb = bias[col];
#pragma unroll
                for (int mtg = 0; mtg < 8; ++mtg)
#pragma unroll
                    for (int r = 0; r < 4; ++r)
                        eT[(ni * 16 + l15) * 136 + mtg * 16 + quad * 4 + r] = f2h(acc[mtg][ntg][r] + bb);
            }
            int dhbase = ((wn & 1) ? 64 : 0) + rnd * 32;
#pragma unroll
            for (int it = 0; it < 8; ++it) {
                int chunk = it * 64 + lane;            // 512 16B-chunks per round
                int d2 = chunk >> 4, c = chunk & 15;
                uint4 v = *(const uint4*)(eT + d2 * 136 + c * 8);
                *(uint4*)(Vtb + (size_t)((b * H_ + h) * DH_ + dhbase + d2) * T_ + t0 + c * 8) = v;
            }
        }
    }
}

// ---------------------------------------------------------------- O-projection GEMM (256^2, f32 out)
__global__ __launch_bounds__(512, 2) void gemm_o256(
    const ushort* __restrict__ A, const ushort* __restrict__ Bt,
    const float* __restrict__ bias, float* __restrict__ Cout)
{
    extern __shared__ char smem[];
    const int tid = threadIdx.x;

    int id = blockIdx.y * 8 + blockIdx.x;        // 256 blocks, 256 % 8 == 0
    id = (id & 7) * 32 + (id >> 3);
    const int bx = id % 8, by = id / 8;

    const int row0 = by * 256, col0 = bx * 256;
    const ushort* Ap = A;
    const ushort* Bp = Bt;

    GEMM256_PRE
    GEMM256_MAIN_LOOP

#pragma unroll
    for (int ntg = 0; ntg < 4; ++ntg) {
        int col = col0 + wn * 64 + ntg * 16 + l15;
        float bb = bias[col];
#pragma unroll
        for (int mtg = 0; mtg < 8; ++mtg) {
            int rowb = row0 + wm * 128 + mtg * 16 + quad * 4;
#pragma unroll
            for (int r = 0; r < 4; ++r)
                Cout[(size_t)(rowb + r) * D_ + col] = acc[mtg][ntg][r] + bb;
        }
    }
}

// ---------------------------------------------------------------- flash attention (S^T / O^T form)
// Q (pre-scaled by 1/sqrt(DH)*log2e), K: [B,T,D] bf16 ; Vt: [B,H,DH,T] f16 ; O: [B,T,D] bf16
__global__ __launch_bounds__(256, 5) void attn_kernel(
    const ushort* __restrict__ Q, const ushort* __restrict__ K,
    const ushort* __restrict__ Vt, ushort* __restrict__ O)
{
    __shared__ __align__(16) char smem[32768];
    uint4*  kS = (uint4*)smem;                 // [64 s][16 chunks], chunk-swizzled
    ushort* vS = (ushort*)(smem + 16384);      // [128 dh][16 slots x 4 halfs], slot ^ (dh&15)

    const int tid = threadIdx.x;
    const int bid = blockIdx.x;
    const int slot = bid >> 3;
    const int g = (bid & 7) + 8 * (slot >> 4);
    const int qx = slot & 15;
    const int b = g >> 4, h = g & 15;

    const int lane = tid & 63, w = tid >> 6, l15 = lane & 15, quad = lane >> 4;

    const int krow = tid >> 4;                       // 0..15
    const int kchunk = (tid & 15) ^ (krow & 7);
    const ushort* kg = K + ((size_t)(b * T_) + krow) * D_ + h * DH_ + kchunk * 8;

    const int vrow = tid >> 3, vc = tid & 7;         // vrow 0..31, chunk 0..7 (8 halfs)
    const ushort* vg = Vt + ((size_t)((b * H_ + h) * DH_) + vrow) * T_ + vc * 8;
    const int vs0 = ((2 * vc    ) ^ (vrow & 15)) * 4;
    const int vs1 = ((2 * vc + 1) ^ (vrow & 15)) * 4;

    const int qts[2] = { qx, 31 - qx };

    for (int e = 0; e < 2; ++e) {
        const int qt = qts[e], q0 = qt * 64;
        const int qbase = q0 + w * 16;               // wave's first q

        short8 aq[4];
        {
            const ushort* qp = Q + ((size_t)(b * T_) + qbase + l15) * D_ + h * DH_ + quad * 8;
#pragma unroll
            for (int ks = 0; ks < 4; ++ks)
                aq[ks] = __builtin_bit_cast(short8, *(const uint4*)(qp + ks * 32));
        }

        f32x4 accO[8] = {};                          // O^T[dh=nt*16+quad*4+r][q=l15]
        float mrow = -INFINITY, lrow = 0.f;

        auto tile = [&](int s0, int stMax, bool diag) {
            __syncthreads();
            const ushort* kp = kg + (size_t)s0 * D_;
#pragma unroll
            for (int j = 0; j < 4; ++j) glds16(kp + (size_t)j * 16 * D_, kS + j * 256 + tid);
            const ushort* vp = vg + s0;
            uint4 vv[4];
#pragma unroll
            for (int j = 0; j < 4; ++j) vv[j] = *(const uint4*)(vp + (size_t)j * 32 * T_);
#pragma unroll
            for (int j = 0; j < 4; ++j) {
                ushort* dst = vS + (j * 32 + vrow) * 64;
                *(uint2*)(dst + vs0) = make_uint2(vv[j].x, vv[j].y);
                *(uint2*)(dst + vs1) = make_uint2(vv[j].z, vv[j].w);
            }
            __syncthreads();

            f32x4 sT[4] = {};
#pragma unroll
            for (int ks = 0; ks < 4; ++ks)
#pragma unroll
                for (int st = 0; st < 4; ++st)
                    if (st < stMax) {
                        int row = st * 16 + l15;
                        short8 ak = __builtin_bit_cast(short8, kS[row * 16 + ((ks * 4 + quad) ^ (row & 7))]);
                        sT[st] = __builtin_amdgcn_mfma_f32_16x16x32_bf16(ak, aq[ks], sT[st], 0, 0, 0);
                    }

            if (diag) {
                const int q = qbase + l15;
                const int st = stMax - 1;
#pragma unroll
                for (int r = 0; r < 4; ++r)
                    if (s0 + st * 16 + quad * 4 + r > q) sT[st][r] = -INFINITY;
            }

            float rmax = -INFINITY;
#pragma unroll
            for (int st = 0; st < 4; ++st)
                if (st < stMax)
#pragma unroll
                    for (int r = 0; r < 4; ++r) rmax = fmaxf(rmax, sT[st][r]);
            rmax = fmaxf(rmax, __shfl_xor(rmax, 16));
            rmax = fmaxf(rmax, __shfl_xor(rmax, 32));
            float mnew  = fmaxf(mrow, rmax);
            float alpha = __builtin_amdgcn_exp2f(mrow - mnew);
            mrow = mnew;

            float psum = 0.f;
            half4 pb[4];
#pragma unroll
            for (int st = 0; st < 4; ++st)
                if (st < stMax) {
                    float p0 = __builtin_amdgcn_exp2f(sT[st][0] - mnew);
                    float p1 = __builtin_amdgcn_exp2f(sT[st][1] - mnew);
                    float p2 = __builtin_amdgcn_exp2f(sT[st][2] - mnew);
                    float p3 = __builtin_amdgcn_exp2f(sT[st][3] - mnew);
                    psum += (p0 + p1) + (p2 + p3);
                    uint2 u;
                    u.x = __builtin_bit_cast(unsigned int, __builtin_amdgcn_cvt_pkrtz(p0, p1));
                    u.y = __builtin_bit_cast(unsigned int, __builtin_amdgcn_cvt_pkrtz(p2, p3));
                    pb[st] = __builtin_bit_cast(half4, u);
                }
            psum += __shfl_xor(psum, 16);
            psum += __shfl_xor(psum, 32);
            lrow = lrow * alpha + psum;
#pragma unroll
            for (int nt = 0; nt < 8; ++nt)
#pragma unroll
                for (int r = 0; r < 4; ++r) accO[nt][r] *= alpha;

#pragma unroll
            for (int st = 0; st < 4; ++st)
                if (st < stMax) {
#pragma unroll
                    for (int nt = 0; nt < 8; ++nt) {
                        int dh = nt * 16 + l15;
                        half4 vf = *(const half4*)(vS + dh * 64 + (((st * 4 + quad) ^ l15) * 4));
                        accO[nt] = __builtin_amdgcn_mfma_f32_16x16x16f16(vf, pb[st], accO[nt], 0, 0, 0);
                    }
                }
        };

        for (int it = 0; it < qt; ++it) tile(it * 64, 4, false);
        tile(qt * 64, w + 1, true);

        __syncthreads();
        ushort* eT = (ushort*)smem + w * 2176;        // [16 q][136 dh-pad]
        float inv = 1.0f / lrow;
#pragma unroll
        for (int nt = 0; nt < 8; ++nt) {
            int dh = nt * 16 + quad * 4;
#pragma unroll
            for (int r = 0; r < 4; ++r)
                eT[l15 * 136 + dh + r] = f2bf(accO[nt][r] * inv);
        }
        for (int idx = lane; idx < 256; idx += 64) {
            int row = idx >> 4, c = idx & 15;
            uint4 v = *(const uint4*)(eT + row * 136 + c * 8);
            *(uint4*)(O + ((size_t)(b * T_) + q0 + w * 16 + row) * D_ + h * DH_ + c * 8) = v;
        }
    }
}

extern "C" void kernel_launch(void* const* d_in, const int* in_sizes, int n_in,
                              void* d_out, int out_size, void* d_ws, size_t ws_size,
                              hipStream_t stream) {
    const float* x  = (const float*)d_in[0];
    const float* Wq = (const float*)d_in[1];
    const float* bq = (const float*)d_in[2];
    const float* Wk = (const float*)d_in[3];
    const float* bk = (const float*)d_in[4];
    const float* Wv = (const float*)d_in[5];
    const float* bv = (const float*)d_in[6];
    const float* Wo = (const float*)d_in[7];
    const float* bo = (const float*)d_in[8];

    char* ws = (char*)d_ws;
    const size_t MB = 1u << 20;
    ushort* xb  = (ushort*)(ws);
    ushort* Wqt = (ushort*)(ws + 32 * MB);
    ushort* Wkt = (ushort*)(ws + 40 * MB);
    ushort* Wvt = (ushort*)(ws + 48 * MB);
    ushort* Wot = (ushort*)(ws + 56 * MB);
    ushort* Qb  = (ushort*)(ws + 64 * MB);
    ushort* Kb  = (ushort*)(ws + 96 * MB);
    ushort* Vtb = (ushort*)(ws + 128 * MB);
    ushort* Ob  = (ushort*)(ws + 160 * MB);

    const int M = B_ * T_;   // 8192
    const float qscale = (float)(0.08838834764831845 * 1.4426950408889634); // 1/sqrt(DH) * log2(e)

    static bool attr_done = false;
    if (!attr_done) {
        (void)hipFuncSetAttribute((const void*)gemm_qkv256,
                                  hipFuncAttributeMaxDynamicSharedMemorySize, 131072);
        (void)hipFuncSetAttribute((const void*)gemm_o256,
                                  hipFuncAttributeMaxDynamicSharedMemorySize, 131072);
        attr_done = true;
    }

    cast_f32_bf16<<<(M * D_) / 1024, 256, 0, stream>>>(x, xb, M * D_);
    dim3 tb(32, 8), tg(D_ / 32, D_ / 32);
    transpose_cast<<<tg, tb, 0, stream>>>(Wq, Wqt);
    transpose_cast<<<tg, tb, 0, stream>>>(Wk, Wkt);
    transpose_cast<<<tg, tb, 0, stream>>>(Wv, Wvt);
    transpose_cast<<<tg, tb, 0, stream>>>(Wo, Wot);

    gemm_qkv256<<<dim3(24, M / 256), 512, 131072, stream>>>(
        xb, Wqt, Wkt, Wvt, bq, bk, bv, Qb, Kb, Vtb, qscale);

    attn_kernel<<<dim3(1024), 256, 0, stream>>>(Qb, Kb, Vtb, Ob);

    gemm_o256<<<dim3(D_ / 256, M / 256), 512, 131072, stream>>>(
        Ob, Wot, bo, (float*)d_out);
}

// Round 3
// 677.177 us; speedup vs baseline: 1.0094x; 1.0094x over previous
//
#include <hip/hip_runtime.h>
#include <hip/hip_bf16.h>

#define B_  4
#define T_  2048
#define D_  2048
#define H_  16
#define DH_ 128
#define KG  2048   // GEMM K (= D_)

typedef __attribute__((ext_vector_type(4))) float f32x4;
typedef __attribute__((ext_vector_type(8))) short short8;
typedef __attribute__((ext_vector_type(4))) _Float16 half4;

__device__ __forceinline__ ushort f2bf(float f) {
    unsigned int u = __builtin_bit_cast(unsigned int, f);
    u += 0x7fffu + ((u >> 16) & 1u);   // RNE
    return (ushort)(u >> 16);
}
__device__ __forceinline__ ushort f2h(float f) {
    return (ushort)(__builtin_bit_cast(unsigned int, __builtin_amdgcn_cvt_pkrtz(f, f)) & 0xffffu);
}

// async global -> LDS, 16B per lane. LDS dst must be wave-uniform base + lane*16.
__device__ __forceinline__ void glds16(const void* g, void* l) {
    __builtin_amdgcn_global_load_lds(
        (const __attribute__((address_space(1))) unsigned int*)g,
        (__attribute__((address_space(3))) unsigned int*)l, 16, 0, 0);
}

// ---------------------------------------------------------------- cast x -> bf16
__global__ void cast_f32_bf16(const float* __restrict__ x, ushort* __restrict__ xb, int n) {
    int i = (blockIdx.x * 256 + threadIdx.x) * 4;
    if (i < n) {
        float4 v = *(const float4*)(x + i);
        ushort4 o;
        o.x = f2bf(v.x); o.y = f2bf(v.y); o.z = f2bf(v.z); o.w = f2bf(v.w);
        *(ushort4*)(xb + i) = o;
    }
}

// ------------------------------------------------- W [k][n] fp32 -> Wt [n][k] bf16
__global__ void transpose_cast(const float* __restrict__ W, ushort* __restrict__ Wt) {
    __shared__ float tile[32][33];
    int tx = threadIdx.x, ty = threadIdx.y;           // 32 x 8
    int n0 = blockIdx.x * 32, k0 = blockIdx.y * 32;
#pragma unroll
    for (int i = 0; i < 4; i++)
        tile[ty + i * 8][tx] = W[(size_t)(k0 + ty + i * 8) * D_ + n0 + tx];
    __syncthreads();
#pragma unroll
    for (int i = 0; i < 4; i++)
        Wt[(size_t)(n0 + ty + i * 8) * D_ + k0 + tx] = f2bf(tile[tx][ty + i * 8]);
}

// ================================================================ 256x256 8-phase GEMM core
// 512 threads = 8 waves (2M x 4N). BK=64. LDS 128KiB: A[2 dbuf][2 region(qm)][128][64]bf16,
// B at +64KiB (region qn). 16B-chunk swizzle ch^=(row&7) on glds SOURCE + ds_read addr.
//
// R2 schedule (earliest-dead staging, uniform per-phase vmcnt(6)):
//   phase:   P1      P2      P3      P4      P5      P6      P7      P8
//   reads:  A00,B00  B01     A01     B00    A10,B10  B11     A11     B10
//   stage:  B10(t1) A00(t2) B01(t2) A01(t2) B00(t2) A10(t3) B11(t3) A11(t3)
//   Read-to-stage distance >= 4 phases for every region (B00->P1, B10->P5 are 4; rest 7).
//   Each STAGE = 2 glds16 (vmcnt units!). Per-phase: issue 1 stage, then vmcnt(6)
//   (3 stages in flight) -> guarantees stage p-4 retired at wait p-1, covering all reads.
//   Stages land only in regions past their last read; barriers: VM6 -> s_barrier ->
//   [compiler lgkm] MFMA -> s_barrier (RAW edge via VM6+BAR1; WAR edge via BAR2).
//   Tail stages clamp kt->31 (garbage into dead regions); VM0 drains before epilogue.

#define LDS_A(d, qm, AF)                                                                   \
  { _Pragma("unroll") for (int mt = 0; mt < 4; ++mt) {                                     \
      AF[mt][0] = __builtin_bit_cast(short8,                                               \
          *(const uint4*)(smem + aAddr0 + (((d)*2 + (qm)) << 14) + mt*2048));              \
      AF[mt][1] = __builtin_bit_cast(short8,                                               \
          *(const uint4*)(smem + aAddr1 + (((d)*2 + (qm)) << 14) + mt*2048));              \
    } }

#define LDS_B(d, qn, BF)                                                                   \
  { _Pragma("unroll") for (int nt = 0; nt < 2; ++nt) {                                     \
      BF[nt][0] = __builtin_bit_cast(short8,                                               \
          *(const uint4*)(smem + bAddr0 + (((d)*2 + (qn)) << 14) + nt*2048));              \
      BF[nt][1] = __builtin_bit_cast(short8,                                               \
          *(const uint4*)(smem + bAddr1 + (((d)*2 + (qn)) << 14) + nt*2048));              \
    } }

#define STAGE_A(d, qm, kt)                                                                 \
  { const ushort* s_ = aSrc + (size_t)(qm) * (64 * KG) + (size_t)(kt) * 64;                \
    char* l_ = ldsT + (((d)*2 + (qm)) << 14);                                              \
    glds16(s_, l_);                                                                        \
    glds16(s_ + (size_t)128 * KG, l_ + 8192); }

#define STAGE_B(d, qn, kt)                                                                 \
  { const ushort* s_ = bSrc + (size_t)(qn) * (32 * KG) + (size_t)(kt) * 64;                \
    char* l_ = ldsT + 65536 + (((d)*2 + (qn)) << 14);                                      \
    glds16(s_, l_);                                                                        \
    glds16(s_ + (size_t)128 * KG, l_ + 8192); }

#define MFMA16(QM, QN, AF, BF)                                                             \
  __builtin_amdgcn_s_setprio(1);                                                           \
  _Pragma("unroll") for (int mt = 0; mt < 4; ++mt)                                         \
    _Pragma("unroll") for (int nt = 0; nt < 2; ++nt)                                       \
      _Pragma("unroll") for (int kk = 0; kk < 2; ++kk)                                     \
        acc[(QM)*4 + mt][(QN)*2 + nt] = __builtin_amdgcn_mfma_f32_16x16x32_bf16(           \
            AF[mt][kk], BF[nt][kk], acc[(QM)*4 + mt][(QN)*2 + nt], 0, 0, 0);               \
  __builtin_amdgcn_s_setprio(0);

#define VM6        asm volatile("s_waitcnt vmcnt(6)" ::: "memory");
#define VM0        asm volatile("s_waitcnt vmcnt(0)" ::: "memory");
#define BARR       __builtin_amdgcn_s_barrier();
#define SCHEDB     __builtin_amdgcn_sched_barrier(0);

#define GEMM256_PRE                                                                        \
    const int lane = tid & 63, w = tid >> 6;                                               \
    const int l15 = lane & 15, quad = lane >> 4;                                           \
    const int wm = w & 1, wn = w >> 1;                                                     \
    const int irow = tid >> 3;                                                             \
    const int chl  = (tid & 7) ^ (irow & 7);                                               \
    const ushort* aSrc = Ap + (size_t)(row0 + irow) * KG + chl * 8;                        \
    const ushort* bSrc = Bp + (size_t)(col0 + ((irow >> 5) << 6) + (irow & 31)) * KG + chl * 8; \
    char* ldsT = smem + tid * 16;                                                          \
    const int sw0 = (quad ^ (l15 & 7)) << 4;                                               \
    const int sw1 = ((4 + quad) ^ (l15 & 7)) << 4;                                         \
    const int aRow = (wm * 64 + l15) * 128;                                                \
    const int bRow = (wn * 32 + l15) * 128;                                                \
    const int aAddr0 = aRow + sw0, aAddr1 = aRow + sw1;                                    \
    const int bAddr0 = 65536 + bRow + sw0, bAddr1 = 65536 + bRow + sw1;

#define GEMM256_MAIN_LOOP                                                                  \
    f32x4 acc[8][4] = {};                                                                  \
    short8 aF[4][2], bF[2][2];                                                             \
    /* prologue mimics steady-state ages: 4 retired-by-loop stages, then 3 in flight */    \
    STAGE_A(0, 0, 0); STAGE_B(0, 1, 0); STAGE_A(0, 1, 0); STAGE_B(0, 0, 0);                \
    STAGE_A(1, 0, 1); STAGE_B(1, 1, 1); STAGE_A(1, 1, 1);                                  \
    VM6; BARR; SCHEDB;                                                                     \
    _Pragma("unroll 1")                                                                    \
    for (int j = 0; j < 16; ++j) {                                                         \
        const int t1 = 2*j + 1;                                                            \
        const int t2 = (2*j + 2 < 32) ? 2*j + 2 : 31;                                      \
        const int t3 = (2*j + 3 < 32) ? 2*j + 3 : 31;                                      \
        /* P1 */ LDS_A(0, 0, aF); LDS_B(0, 0, bF); STAGE_B(1, 0, t1);                      \
                 VM6; BARR; MFMA16(0, 0, aF, bF); BARR; SCHEDB;                            \
        /* P2 */ LDS_B(0, 1, bF); STAGE_A(0, 0, t2);                                       \
                 VM6; BARR; MFMA16(0, 1, aF, bF); BARR; SCHEDB;                            \
        /* P3 */ LDS_A(0, 1, aF); STAGE_B(0, 1, t2);                                       \
                 VM6; BARR; MFMA16(1, 1, aF, bF); BARR; SCHEDB;                            \
        /* P4 */ LDS_B(0, 0, bF); STAGE_A(0, 1, t2);                                       \
                 VM6; BARR; MFMA16(1, 0, aF, bF); BARR; SCHEDB;                            \
        /* P5 */ LDS_A(1, 0, aF); LDS_B(1, 0, bF); STAGE_B(0, 0, t2);                      \
                 VM6; BARR; MFMA16(0, 0, aF, bF); BARR; SCHEDB;                            \
        /* P6 */ LDS_B(1, 1, bF); STAGE_A(1, 0, t3);                                       \
                 VM6; BARR; MFMA16(0, 1, aF, bF); BARR; SCHEDB;                            \
        /* P7 */ LDS_A(1, 1, aF); STAGE_B(1, 1, t3);                                       \
                 VM6; BARR; MFMA16(1, 1, aF, bF); BARR; SCHEDB;                            \
        /* P8 */ LDS_B(1, 0, bF); STAGE_A(1, 1, t3);                                       \
                 VM6; BARR; MFMA16(1, 0, aF, bF); BARR; SCHEDB;                            \
    }                                                                                      \
    VM0; BARR;

// ---------------------------------------------------------------- merged QKV GEMM (256^2)
// 768 blocks. XCD x (= linear_id % 8) permanently owns weight col-panels bx in
// {3x, 3x+1, 3x+2} (3 MB, L2-resident); A-panels stream, shared by the 3 co-running
// bx blocks of the same by on that XCD. sel = bx>>3 picks {Q,K,V}.
__global__ __launch_bounds__(512, 2) void gemm_qkv256(
    const ushort* __restrict__ A,
    const ushort* __restrict__ Wq, const ushort* __restrict__ Wk, const ushort* __restrict__ Wv,
    const float* __restrict__ bq, const float* __restrict__ bk, const float* __restrict__ bv,
    ushort* __restrict__ Qb, ushort* __restrict__ Kb, ushort* __restrict__ Vtb,
    float qscale)
{
    extern __shared__ char smem[];
    const int tid = threadIdx.x;

    const int lid = blockIdx.y * 24 + blockIdx.x;
    const int xcd = lid & 7, jj = lid >> 3;          // jj in [0,96)
    const int bx  = 3 * xcd + jj % 3;
    const int by  = jj / 3;

    const int sel  = bx >> 3;                    // 0=Q 1=K 2=V
    const int row0 = by * 256, col0 = (bx & 7) * 256;
    const ushort* Ap = A;
    const ushort* Bp = (sel == 0) ? Wq : (sel == 1) ? Wk : Wv;
    const float* bias = (sel == 0) ? bq : (sel == 1) ? bk : bv;
    const float oscale = (sel == 0) ? qscale : 1.0f;

    GEMM256_PRE
    GEMM256_MAIN_LOOP

    if (sel < 2) {
        ushort* Cout = sel ? Kb : Qb;
        float bb[4];
#pragma unroll
        for (int ntg = 0; ntg < 4; ++ntg) bb[ntg] = bias[col0 + wn * 64 + ntg * 16 + l15];
        // ntg innermost: each 128B line (row, wave's 64-col span) completed by 4
        // consecutive stores -> no partial-dirty-line churn in L2.
#pragma unroll
        for (int mtg = 0; mtg < 8; ++mtg) {
            int rowb = row0 + wm * 128 + mtg * 16 + quad * 4;
#pragma unroll
            for (int r = 0; r < 4; ++r)
#pragma unroll
                for (int ntg = 0; ntg < 4; ++ntg) {
                    int col = col0 + wn * 64 + ntg * 16 + l15;
                    Cout[(size_t)(rowb + r) * D_ + col] = f2bf((acc[mtg][ntg][r] + bb[ntg]) * oscale);
                }
        }
    } else {
        // V path: per-wave transpose (two 32-dh rounds) -> f16 [B,H,DH,T]
        const int b = row0 >> 11, t0 = (row0 & (T_ - 1)) + wm * 128;
        const int h = (col0 + wn * 64) >> 7;
        ushort* eT = (ushort*)smem + w * (32 * 136);   // [32 dh][136 t-pad], wave-private
#pragma unroll 1
        for (int rnd = 0; rnd < 2; ++rnd) {
#pragma unroll
            for (int ni = 0; ni < 2; ++ni) {
                int ntg = rnd * 2 + ni;
                int col = col0 + wn * 64 + ntg * 16 + l15;
                float bb = bias[col];
#pragma unroll
                for (int mtg = 0; mtg < 8; ++mtg)
#pragma unroll
                    for (int r = 0; r < 4; ++r)
                        eT[(ni * 16 + l15) * 136 + mtg * 16 + quad * 4 + r] = f2h(acc[mtg][ntg][r] + bb);
            }
            int dhbase = ((wn & 1) ? 64 : 0) + rnd * 32;
#pragma unroll
            for (int it = 0; it < 8; ++it) {
                int chunk = it * 64 + lane;            // 512 16B-chunks per round
                int d2 = chunk >> 4, c = chunk & 15;
                uint4 v = *(const uint4*)(eT + d2 * 136 + c * 8);
                *(uint4*)(Vtb + (size_t)((b * H_ + h) * DH_ + dhbase + d2) * T_ + t0 + c * 8) = v;
            }
        }
    }
}

// ---------------------------------------------------------------- O-projection GEMM (256^2, f32 out)
// Natural grid order: linear id = by*8+bx -> XCD = bx. Each XCD owns exactly one
// 1 MB weight col-panel (L2-resident). No swizzle needed.
__global__ __launch_bounds__(512, 2) void gemm_o256(
    const ushort* __restrict__ A, const ushort* __restrict__ Bt,
    const float* __restrict__ bias, float* __restrict__ Cout)
{
    extern __shared__ char smem[];
    const int tid = threadIdx.x;

    const int bx = blockIdx.x, by = blockIdx.y;
    const int row0 = by * 256, col0 = bx * 256;
    const ushort* Ap = A;
    const ushort* Bp = Bt;

    GEMM256_PRE
    GEMM256_MAIN_LOOP

    float bb[4];
#pragma unroll
    for (int ntg = 0; ntg < 4; ++ntg) bb[ntg] = bias[col0 + wn * 64 + ntg * 16 + l15];
#pragma unroll
    for (int mtg = 0; mtg < 8; ++mtg) {
        int rowb = row0 + wm * 128 + mtg * 16 + quad * 4;
#pragma unroll
        for (int r = 0; r < 4; ++r)
#pragma unroll
            for (int ntg = 0; ntg < 4; ++ntg) {
                int col = col0 + wn * 64 + ntg * 16 + l15;
                Cout[(size_t)(rowb + r) * D_ + col] = acc[mtg][ntg][r] + bb[ntg];
            }
    }
}

// ---------------------------------------------------------------- flash attention (S^T / O^T form)
// Q (pre-scaled by 1/sqrt(DH)*log2e), K: [B,T,D] bf16 ; Vt: [B,H,DH,T] f16 ; O: [B,T,D] bf16
__global__ __launch_bounds__(256, 5) void attn_kernel(
    const ushort* __restrict__ Q, const ushort* __restrict__ K,
    const ushort* __restrict__ Vt, ushort* __restrict__ O)
{
    __shared__ __align__(16) char smem[32768];
    uint4*  kS = (uint4*)smem;                 // [64 s][16 chunks], chunk-swizzled
    ushort* vS = (ushort*)(smem + 16384);      // [128 dh][16 slots x 4 halfs], slot ^ (dh&15)

    const int tid = threadIdx.x;
    const int bid = blockIdx.x;
    const int slot = bid >> 3;
    const int g = (bid & 7) + 8 * (slot >> 4);
    const int qx = slot & 15;
    const int b = g >> 4, h = g & 15;

    const int lane = tid & 63, w = tid >> 6, l15 = lane & 15, quad = lane >> 4;

    const int krow = tid >> 4;                       // 0..15
    const int kchunk = (tid & 15) ^ (krow & 7);
    const ushort* kg = K + ((size_t)(b * T_) + krow) * D_ + h * DH_ + kchunk * 8;

    const int vrow = tid >> 3, vc = tid & 7;         // vrow 0..31, chunk 0..7 (8 halfs)
    const ushort* vg = Vt + ((size_t)((b * H_ + h) * DH_) + vrow) * T_ + vc * 8;
    const int vs0 = ((2 * vc    ) ^ (vrow & 15)) * 4;
    const int vs1 = ((2 * vc + 1) ^ (vrow & 15)) * 4;

    const int qts[2] = { qx, 31 - qx };

    for (int e = 0; e < 2; ++e) {
        const int qt = qts[e], q0 = qt * 64;
        const int qbase = q0 + w * 16;               // wave's first q

        short8 aq[4];
        {
            const ushort* qp = Q + ((size_t)(b * T_) + qbase + l15) * D_ + h * DH_ + quad * 8;
#pragma unroll
            for (int ks = 0; ks < 4; ++ks)
                aq[ks] = __builtin_bit_cast(short8, *(const uint4*)(qp + ks * 32));
        }

        f32x4 accO[8] = {};                          // O^T[dh=nt*16+quad*4+r][q=l15]
        float mrow = -INFINITY, lrow = 0.f;

        auto tile = [&](int s0, int stMax, bool diag) {
            __syncthreads();
            const ushort* kp = kg + (size_t)s0 * D_;
#pragma unroll
            for (int j = 0; j < 4; ++j) glds16(kp + (size_t)j * 16 * D_, kS + j * 256 + tid);
            const ushort* vp = vg + s0;
            uint4 vv[4];
#pragma unroll
            for (int j = 0; j < 4; ++j) vv[j] = *(const uint4*)(vp + (size_t)j * 32 * T_);
#pragma unroll
            for (int j = 0; j < 4; ++j) {
                ushort* dst = vS + (j * 32 + vrow) * 64;
                *(uint2*)(dst + vs0) = make_uint2(vv[j].x, vv[j].y);
                *(uint2*)(dst + vs1) = make_uint2(vv[j].z, vv[j].w);
            }
            __syncthreads();

            f32x4 sT[4] = {};
#pragma unroll
            for (int ks = 0; ks < 4; ++ks)
#pragma unroll
                for (int st = 0; st < 4; ++st)
                    if (st < stMax) {
                        int row = st * 16 + l15;
                        short8 ak = __builtin_bit_cast(short8, kS[row * 16 + ((ks * 4 + quad) ^ (row & 7))]);
                        sT[st] = __builtin_amdgcn_mfma_f32_16x16x32_bf16(ak, aq[ks], sT[st], 0, 0, 0);
                    }

            if (diag) {
                const int q = qbase + l15;
                const int st = stMax - 1;
#pragma unroll
                for (int r = 0; r < 4; ++r)
                    if (s0 + st * 16 + quad * 4 + r > q) sT[st][r] = -INFINITY;
            }

            float rmax = -INFINITY;
#pragma unroll
            for (int st = 0; st < 4; ++st)
                if (st < stMax)
#pragma unroll
                    for (int r = 0; r < 4; ++r) rmax = fmaxf(rmax, sT[st][r]);
            rmax = fmaxf(rmax, __shfl_xor(rmax, 16));
            rmax = fmaxf(rmax, __shfl_xor(rmax, 32));
            float mnew  = fmaxf(mrow, rmax);
            float alpha = __builtin_amdgcn_exp2f(mrow - mnew);
            mrow = mnew;

            float psum = 0.f;
            half4 pb[4];
#pragma unroll
            for (int st = 0; st < 4; ++st)
                if (st < stMax) {
                    float p0 = __builtin_amdgcn_exp2f(sT[st][0] - mnew);
                    float p1 = __builtin_amdgcn_exp2f(sT[st][1] - mnew);
                    float p2 = __builtin_amdgcn_exp2f(sT[st][2] - mnew);
                    float p3 = __builtin_amdgcn_exp2f(sT[st][3] - mnew);
                    psum += (p0 + p1) + (p2 + p3);
                    uint2 u;
                    u.x = __builtin_bit_cast(unsigned int, __builtin_amdgcn_cvt_pkrtz(p0, p1));
                    u.y = __builtin_bit_cast(unsigned int, __builtin_amdgcn_cvt_pkrtz(p2, p3));
                    pb[st] = __builtin_bit_cast(half4, u);
                }
            psum += __shfl_xor(psum, 16);
            psum += __shfl_xor(psum, 32);
            lrow = lrow * alpha + psum;
#pragma unroll
            for (int nt = 0; nt < 8; ++nt)
#pragma unroll
                for (int r = 0; r < 4; ++r) accO[nt][r] *= alpha;

#pragma unroll
            for (int st = 0; st < 4; ++st)
                if (st < stMax) {
#pragma unroll
                    for (int nt = 0; nt < 8; ++nt) {
                        int dh = nt * 16 + l15;
                        half4 vf = *(const half4*)(vS + dh * 64 + (((st * 4 + quad) ^ l15) * 4));
                        accO[nt] = __builtin_amdgcn_mfma_f32_16x16x16f16(vf, pb[st], accO[nt], 0, 0, 0);
                    }
                }
        };

        for (int it = 0; it < qt; ++it) tile(it * 64, 4, false);
        tile(qt * 64, w + 1, true);

        __syncthreads();
        ushort* eT = (ushort*)smem + w * 2176;        // [16 q][136 dh-pad]
        float inv = 1.0f / lrow;
#pragma unroll
        for (int nt = 0; nt < 8; ++nt) {
            int dh = nt * 16 + quad * 4;
#pragma unroll
            for (int r = 0; r < 4; ++r)
                eT[l15 * 136 + dh + r] = f2bf(accO[nt][r] * inv);
        }
        for (int idx = lane; idx < 256; idx += 64) {
            int row = idx >> 4, c = idx & 15;
            uint4 v = *(const uint4*)(eT + row * 136 + c * 8);
            *(uint4*)(O + ((size_t)(b * T_) + q0 + w * 16 + row) * D_ + h * DH_ + c * 8) = v;
        }
    }
}

extern "C" void kernel_launch(void* const* d_in, const int* in_sizes, int n_in,
                              void* d_out, int out_size, void* d_ws, size_t ws_size,
                              hipStream_t stream) {
    const float* x  = (const float*)d_in[0];
    const float* Wq = (const float*)d_in[1];
    const float* bq = (const float*)d_in[2];
    const float* Wk = (const float*)d_in[3];
    const float* bk = (const float*)d_in[4];
    const float* Wv = (const float*)d_in[5];
    const float* bv = (const float*)d_in[6];
    const float* Wo = (const float*)d_in[7];
    const float* bo = (const float*)d_in[8];

    char* ws = (char*)d_ws;
    const size_t MB = 1u << 20;
    ushort* xb  = (ushort*)(ws);
    ushort* Wqt = (ushort*)(ws + 32 * MB);
    ushort* Wkt = (ushort*)(ws + 40 * MB);
    ushort* Wvt = (ushort*)(ws + 48 * MB);
    ushort* Wot = (ushort*)(ws + 56 * MB);
    ushort* Qb  = (ushort*)(ws + 64 * MB);
    ushort* Kb  = (ushort*)(ws + 96 * MB);
    ushort* Vtb = (ushort*)(ws + 128 * MB);
    ushort* Ob  = (ushort*)(ws + 160 * MB);

    const int M = B_ * T_;   // 8192
    const float qscale = (float)(0.08838834764831845 * 1.4426950408889634); // 1/sqrt(DH) * log2(e)

    static bool attr_done = false;
    if (!attr_done) {
        (void)hipFuncSetAttribute((const void*)gemm_qkv256,
                                  hipFuncAttributeMaxDynamicSharedMemorySize, 131072);
        (void)hipFuncSetAttribute((const void*)gemm_o256,
                                  hipFuncAttributeMaxDynamicSharedMemorySize, 131072);
        attr_done = true;
    }

    cast_f32_bf16<<<(M * D_) / 1024, 256, 0, stream>>>(x, xb, M * D_);
    dim3 tb(32, 8), tg(D_ / 32, D_ / 32);
    transpose_cast<<<tg, tb, 0, stream>>>(Wq, Wqt);
    transpose_cast<<<tg, tb, 0, stream>>>(Wk, Wkt);
    transpose_cast<<<tg, tb, 0, stream>>>(Wv, Wvt);
    transpose_cast<<<tg, tb, 0, stream>>>(Wo, Wot);

    gemm_qkv256<<<dim3(24, M / 256), 512, 131072, stream>>>(
        xb, Wqt, Wkt, Wvt, bq, bk, bv, Qb, Kb, Vtb, qscale);

    attn_kernel<<<dim3(1024), 256, 0, stream>>>(Qb, Kb, Vtb, Ob);

    gemm_o256<<<dim3(D_ / 256, M / 256), 512, 131072, stream>>>(
        Ob, Wot, bo, (float*)d_out);
}

// Round 4
// 639.150 us; speedup vs baseline: 1.0695x; 1.0595x over previous
//
#include <hip/hip_runtime.h>
#include <hip/hip_bf16.h>

#define B_  4
#define T_  2048
#define D_  2048
#define H_  16
#define DH_ 128

typedef __attribute__((ext_vector_type(4))) float f32x4;
typedef __attribute__((ext_vector_type(8))) short short8;
typedef __attribute__((ext_vector_type(4))) _Float16 half4;

__device__ __forceinline__ ushort f2bf(float f) {
    unsigned int u = __builtin_bit_cast(unsigned int, f);
    u += 0x7fffu + ((u >> 16) & 1u);   // RNE
    return (ushort)(u >> 16);
}
__device__ __forceinline__ ushort f2h(float f) {
    return (ushort)(__builtin_bit_cast(unsigned int, __builtin_amdgcn_cvt_pkrtz(f, f)) & 0xffffu);
}

// async global -> LDS, 16B per lane. LDS dst must be wave-uniform base + lane*16.
__device__ __forceinline__ void glds16(const void* g, void* l) {
    __builtin_amdgcn_global_load_lds(
        (const __attribute__((address_space(1))) unsigned int*)g,
        (__attribute__((address_space(3))) unsigned int*)l, 16, 0, 0);
}

// ---------------------------------------------------------------- cast x -> bf16
__global__ void cast_f32_bf16(const float* __restrict__ x, ushort* __restrict__ xb, int n) {
    int i = (blockIdx.x * 256 + threadIdx.x) * 4;
    if (i < n) {
        float4 v = *(const float4*)(x + i);
        ushort4 o;
        o.x = f2bf(v.x); o.y = f2bf(v.y); o.z = f2bf(v.z); o.w = f2bf(v.w);
        *(ushort4*)(xb + i) = o;
    }
}

// ------------------------------------------------- 4x fused: W [k][n] fp32 -> Wt [n][k] bf16
__global__ void transpose_cast4(
    const float* __restrict__ W0, const float* __restrict__ W1,
    const float* __restrict__ W2, const float* __restrict__ W3,
    ushort* __restrict__ T0, ushort* __restrict__ T1,
    ushort* __restrict__ T2, ushort* __restrict__ T3)
{
    const int z = blockIdx.z;
    const float* W = (z == 0) ? W0 : (z == 1) ? W1 : (z == 2) ? W2 : W3;
    ushort* Wt     = (z == 0) ? T0 : (z == 1) ? T1 : (z == 2) ? T2 : T3;
    __shared__ float tile[32][33];
    int tx = threadIdx.x, ty = threadIdx.y;           // 32 x 8
    int n0 = blockIdx.x * 32, k0 = blockIdx.y * 32;
#pragma unroll
    for (int i = 0; i < 4; i++)
        tile[ty + i * 8][tx] = W[(size_t)(k0 + ty + i * 8) * D_ + n0 + tx];
    __syncthreads();
#pragma unroll
    for (int i = 0; i < 4; i++)
        Wt[(size_t)(n0 + ty + i * 8) * D_ + k0 + tx] = f2bf(tile[tx][ty + i * 8]);
}

// ---------------------------------------------------------------- merged QKV GEMM (128^2, proven)
// A [8192][2048] bf16; three weight mats [2048][2048] (row = out-col, b^T form).
// grid (48, 64): sel = x>>4 picks {Q,K,V}; V path emits f16 [B,H,DH,T].
__global__ __launch_bounds__(256, 3) void gemm_qkv(
    const ushort* __restrict__ A,
    const ushort* __restrict__ Wq, const ushort* __restrict__ Wk, const ushort* __restrict__ Wv,
    const float* __restrict__ bq, const float* __restrict__ bk, const float* __restrict__ bv,
    ushort* __restrict__ Qb, ushort* __restrict__ Kb, ushort* __restrict__ Vtb,
    float qscale)
{
    extern __shared__ char smem[];
    uint4* sA = (uint4*)smem;              // [128 rows][4 chunks], slot c holds chunk c^sw(row)
    uint4* sB = (uint4*)(smem + 8192);

    const int tid  = threadIdx.x;
    const int sel  = blockIdx.x >> 4;           // 0=Q 1=K 2=V
    const int row0 = blockIdx.y * 128, col0 = (blockIdx.x & 15) * 128;
    const ushort* Bt = (sel == 0) ? Wq : (sel == 1) ? Wk : Wv;
    const float* bias = (sel == 0) ? bq : (sel == 1) ? bk : bv;
    const float oscale = (sel == 0) ? qscale : 1.0f;
    const int K = D_, N = D_;

    const int mA = tid >> 2, g = tid & 3;
    const int gc = g ^ ((mA >> 2) & 3);
    const ushort* pa0 = A  + (size_t)(row0 + mA) * K + gc * 8;
    const ushort* pb0 = Bt + (size_t)(col0 + mA) * K + gc * 8;

    const int lane = tid & 63, w = tid >> 6;
    const int l15 = lane & 15, quad = lane >> 4;
    const int wm = w & 1, wn = w >> 1;
    const int csel = quad ^ ((l15 >> 2) & 3);
    int aoff[4], boff[4];
#pragma unroll
    for (int mt = 0; mt < 4; mt++) aoff[mt] = (wm * 64 + mt * 16 + l15) * 4 + csel;
#pragma unroll
    for (int nt = 0; nt < 4; nt++) boff[nt] = (wn * 64 + nt * 16 + l15) * 4 + csel;

    f32x4 acc[4][4] = {};

    const int kIter = K >> 5;
    for (int kt = 0; kt < kIter; ++kt) {
        if (kt) __syncthreads();
        glds16(pa0 + kt * 32,                     sA + tid);
        glds16(pa0 + kt * 32 + (size_t)64 * K,    sA + tid + 256);
        glds16(pb0 + kt * 32,                     sB + tid);
        glds16(pb0 + kt * 32 + (size_t)64 * K,    sB + tid + 256);
        __syncthreads();
        short8 af[4], bfr[4];
#pragma unroll
        for (int mt = 0; mt < 4; mt++) af[mt]  = __builtin_bit_cast(short8, sA[aoff[mt]]);
#pragma unroll
        for (int nt = 0; nt < 4; nt++) bfr[nt] = __builtin_bit_cast(short8, sB[boff[nt]]);
#pragma unroll
        for (int mt = 0; mt < 4; mt++)
#pragma unroll
            for (int nt = 0; nt < 4; nt++)
                acc[mt][nt] = __builtin_amdgcn_mfma_f32_16x16x32_bf16(af[mt], bfr[nt], acc[mt][nt], 0, 0, 0);
    }

    if (sel < 2) {
        ushort* Cout = (sel == 0) ? Qb : Kb;
#pragma unroll
        for (int nt = 0; nt < 4; nt++) {
            int col = col0 + wn * 64 + nt * 16 + l15;
            float bb = bias[col];
#pragma unroll
            for (int mt = 0; mt < 4; mt++) {
                int rowb = row0 + wm * 64 + mt * 16 + quad * 4;
#pragma unroll
                for (int r = 0; r < 4; ++r)
                    Cout[(size_t)(rowb + r) * N + col] = f2bf((acc[mt][nt][r] + bb) * oscale);
            }
        }
    } else {
        // V path: transpose 128x128 tile through LDS, emit f16 [B,H,DH,T]
        __syncthreads();
        ushort* tr = (ushort*)smem;        // [128 dh][136]
#pragma unroll
        for (int nt = 0; nt < 4; nt++) {
            int cl = wn * 64 + nt * 16 + l15;
            float bb = bias[col0 + cl];
#pragma unroll
            for (int mt = 0; mt < 4; mt++) {
                int rl = wm * 64 + mt * 16 + quad * 4;
#pragma unroll
                for (int r = 0; r < 4; ++r)
                    tr[cl * 136 + rl + r] = f2h(acc[mt][nt][r] + bb);
            }
        }
        __syncthreads();
        int b = row0 >> 11, t0 = row0 & (T_ - 1), h = col0 >> 7;
        for (int idx = tid; idx < 2048; idx += 256) {
            int dh = idx >> 4, c = idx & 15;
            uint4 v = *(const uint4*)(tr + dh * 136 + c * 8);
            *(uint4*)(Vtb + (size_t)((b * H_ + h) * DH_ + dh) * T_ + t0 + c * 8) = v;
        }
    }
}

// ---------------------------------------------------------------- O-projection GEMM (f32 out, proven)
__global__ __launch_bounds__(256, 3) void gemm_bt_f32(
    const ushort* __restrict__ A, const ushort* __restrict__ Bt,
    const float* __restrict__ bias, float* __restrict__ Cout,
    int M, int N, int K)
{
    extern __shared__ char smem[];
    uint4* sA = (uint4*)smem;
    uint4* sB = (uint4*)(smem + 8192);

    const int tid  = threadIdx.x;
    const int row0 = blockIdx.y * 128, col0 = blockIdx.x * 128;

    const int mA = tid >> 2, g = tid & 3;
    const int gc = g ^ ((mA >> 2) & 3);
    const ushort* pa0 = A  + (size_t)(row0 + mA) * K + gc * 8;
    const ushort* pb0 = Bt + (size_t)(col0 + mA) * K + gc * 8;

    const int lane = tid & 63, w = tid >> 6;
    const int l15 = lane & 15, quad = lane >> 4;
    const int wm = w & 1, wn = w >> 1;
    const int csel = quad ^ ((l15 >> 2) & 3);
    int aoff[4], boff[4];
#pragma unroll
    for (int mt = 0; mt < 4; mt++) aoff[mt] = (wm * 64 + mt * 16 + l15) * 4 + csel;
#pragma unroll
    for (int nt = 0; nt < 4; nt++) boff[nt] = (wn * 64 + nt * 16 + l15) * 4 + csel;

    f32x4 acc[4][4] = {};

    const int kIter = K >> 5;
    for (int kt = 0; kt < kIter; ++kt) {
        if (kt) __syncthreads();
        glds16(pa0 + kt * 32,                     sA + tid);
        glds16(pa0 + kt * 32 + (size_t)64 * K,    sA + tid + 256);
        glds16(pb0 + kt * 32,                     sB + tid);
        glds16(pb0 + kt * 32 + (size_t)64 * K,    sB + tid + 256);
        __syncthreads();
        short8 af[4], bfr[4];
#pragma unroll
        for (int mt = 0; mt < 4; mt++) af[mt]  = __builtin_bit_cast(short8, sA[aoff[mt]]);
#pragma unroll
        for (int nt = 0; nt < 4; nt++) bfr[nt] = __builtin_bit_cast(short8, sB[boff[nt]]);
#pragma unroll
        for (int mt = 0; mt < 4; mt++)
#pragma unroll
            for (int nt = 0; nt < 4; nt++)
                acc[mt][nt] = __builtin_amdgcn_mfma_f32_16x16x32_bf16(af[mt], bfr[nt], acc[mt][nt], 0, 0, 0);
    }

#pragma unroll
    for (int nt = 0; nt < 4; nt++) {
        int col = col0 + wn * 64 + nt * 16 + l15;
        float bb = bias[col];
#pragma unroll
        for (int mt = 0; mt < 4; mt++) {
            int rowb = row0 + wm * 64 + mt * 16 + quad * 4;
#pragma unroll
            for (int r = 0; r < 4; ++r)
                Cout[(size_t)(rowb + r) * N + col] = acc[mt][nt][r] + bb;
        }
    }
}

// ---------------------------------------------------------------- flash attention (S^T / O^T form)
// Q (pre-scaled by 1/sqrt(DH)*log2e), K: [B,T,D] bf16 ; Vt: [B,H,DH,T] f16 ; O: [B,T,D] bf16
// R3: K AND V staged via glds16; next-tile K/V prefetched mid-tile (after QK^T barrier)
// so staging latency hides under softmax+PV. V double-buffered (48 KiB LDS, 3 blocks/CU).
// V LDS layout: [128 dh][8 slot16 of 16B], slot16 ^= (dh&7); inverse swizzle on the per-lane
// global source (LDS dst stays linear = glds16-compatible). PV ds_read_b64 stays at the
// 4-lanes-per-8B b64 floor. Defer-max (T13, THR=8 in log2 domain): skip O-rescale when
// __all(rmax <= mrow+8) -> P bounded by 2^8 (f16-safe).
__global__ __launch_bounds__(256, 3) void attn_kernel(
    const ushort* __restrict__ Q, const ushort* __restrict__ K,
    const ushort* __restrict__ Vt, ushort* __restrict__ O)
{
    __shared__ __align__(16) char smem[49152];
    uint4*  kS = (uint4*)smem;                 // [64 s][16 chunks], chunk-swizzled (16 KiB)
    ushort* vS = (ushort*)(smem + 16384);      // 2 x [128 dh][64 halfs] (16 KiB each)

    const int tid = threadIdx.x;
    // XCD swizzle: all 16 q-blocks of head-group g land on xcd = g%8
    const int bid = blockIdx.x;
    const int slot = bid >> 3;
    const int g = (bid & 7) + 8 * (slot >> 4);
    const int qx = slot & 15;
    const int b = g >> 4, h = g & 15;

    const int lane = tid & 63, w = tid >> 6, l15 = lane & 15, quad = lane >> 4;

    const int krow = tid >> 4;                       // 0..15
    const int kchunk = (tid & 15) ^ (krow & 7);
    const ushort* kg = K + ((size_t)(b * T_) + krow) * D_ + h * DH_ + kchunk * 8;

    // V via glds16: per j-block of 32 dh rows, thread covers row (tid>>3), slot16 (tid&7).
    // LDS linear dst = vS + j*4096B + tid*16B (wave-uniform base + lane*16). Source slot
    // pre-swizzled: (tid&7) ^ ((tid>>3)&7).
    const int vdh = tid >> 3;                        // 0..31
    const int vslot = (tid & 7) ^ (vdh & 7);
    const ushort* vg = Vt + ((size_t)((b * H_ + h) * DH_) + vdh) * T_ + vslot * 8;
    char* vdst = smem + 16384 + tid * 16;

    const int qts[2] = { qx, 31 - qx };

    for (int e = 0; e < 2; ++e) {
        const int qt = qts[e], q0 = qt * 64;
        const int qbase = q0 + w * 16;               // wave's first q

        // Q B-fragments in registers (B[k=quad*8+j][n=l15])
        short8 aq[4];
        {
            const ushort* qp = Q + ((size_t)(b * T_) + qbase + l15) * D_ + h * DH_ + quad * 8;
#pragma unroll
            for (int ks = 0; ks < 4; ++ks)
                aq[ks] = __builtin_bit_cast(short8, *(const uint4*)(qp + ks * 32));
        }

        f32x4 accO[8] = {};                          // O^T[dh=nt*16+quad*4+r][q=l15]
        float mrow = -INFINITY, lrow = 0.f;

        __syncthreads();                             // prior epilogue readers done
        // prologue: stage tile 0 (K -> kS, V -> vS buf0)
#pragma unroll
        for (int j = 0; j < 4; ++j) glds16(kg + (size_t)j * 16 * D_, kS + j * 256 + tid);
#pragma unroll
        for (int j = 0; j < 4; ++j) glds16(vg + (size_t)j * 32 * T_, vdst + j * 4096);

        for (int i = 0; i <= qt; ++i) {
            const int s0 = i * 64;
            const bool diag = (i == qt);
            const int stMax = diag ? (w + 1) : 4;

            __syncthreads();                         // K(i)/V(i) landed (vmcnt0 drain); prev PV done

            // S^T = K Q^T : rows s (from K), cols q
            f32x4 sT[4] = {};
#pragma unroll
            for (int ks = 0; ks < 4; ++ks)
#pragma unroll
                for (int st = 0; st < 4; ++st)
                    if (st < stMax) {
                        int row = st * 16 + l15;
                        short8 ak = __builtin_bit_cast(short8, kS[row * 16 + ((ks * 4 + quad) ^ (row & 7))]);
                        sT[st] = __builtin_amdgcn_mfma_f32_16x16x32_bf16(ak, aq[ks], sT[st], 0, 0, 0);
                    }

            __syncthreads();                         // all waves done reading kS

            if (i < qt) {                            // prefetch tile i+1 under softmax+PV
                const ushort* kp = kg + (size_t)(s0 + 64) * D_;
#pragma unroll
                for (int j = 0; j < 4; ++j) glds16(kp + (size_t)j * 16 * D_, kS + j * 256 + tid);
                const ushort* vp = vg + s0 + 64;
                char* vd = vdst + (((i + 1) & 1) << 14);
#pragma unroll
                for (int j = 0; j < 4; ++j) glds16(vp + (size_t)j * 32 * T_, vd + j * 4096);
            }

            // causal mask: only the st==w subtile straddles the diagonal
            if (diag) {
                const int q = qbase + l15;
                const int st = stMax - 1;
#pragma unroll
                for (int r = 0; r < 4; ++r)
                    if (s0 + st * 16 + quad * 4 + r > q) sT[st][r] = -INFINITY;
            }

            // online softmax with defer-max
            float rmax = -INFINITY;
#pragma unroll
            for (int st = 0; st < 4; ++st)
                if (st < stMax)
#pragma unroll
                    for (int r = 0; r < 4; ++r) rmax = fmaxf(rmax, sT[st][r]);
            rmax = fmaxf(rmax, __shfl_xor(rmax, 16));
            rmax = fmaxf(rmax, __shfl_xor(rmax, 32));
            if (!__all(rmax <= mrow + 8.0f)) {
                float mnew  = fmaxf(mrow, rmax);
                float alpha = __builtin_amdgcn_exp2f(mrow - mnew);
                mrow = mnew;
                lrow *= alpha;
#pragma unroll
                for (int nt = 0; nt < 8; ++nt)
#pragma unroll
                    for (int r = 0; r < 4; ++r) accO[nt][r] *= alpha;
            }

            float psum = 0.f;
            half4 pb[4];
#pragma unroll
            for (int st = 0; st < 4; ++st)
                if (st < stMax) {
                    float p0 = __builtin_amdgcn_exp2f(sT[st][0] - mrow);
                    float p1 = __builtin_amdgcn_exp2f(sT[st][1] - mrow);
                    float p2 = __builtin_amdgcn_exp2f(sT[st][2] - mrow);
                    float p3 = __builtin_amdgcn_exp2f(sT[st][3] - mrow);
                    psum += (p0 + p1) + (p2 + p3);
                    uint2 u;
                    u.x = __builtin_bit_cast(unsigned int, __builtin_amdgcn_cvt_pkrtz(p0, p1));
                    u.y = __builtin_bit_cast(unsigned int, __builtin_amdgcn_cvt_pkrtz(p2, p3));
                    pb[st] = __builtin_bit_cast(half4, u);
                }
            psum += __shfl_xor(psum, 16);
            psum += __shfl_xor(psum, 32);
            lrow += psum;

            // O^T += V P^T : A-frag = V[dh][s16-slot] from swizzled vS buf (i&1)
            const ushort* vb = vS + ((i & 1) << 13);   // 8192 ushorts per buffer
#pragma unroll
            for (int st = 0; st < 4; ++st)
                if (st < stMax) {
                    const int s8 = st * 4 + quad;
                    const int off = (((s8 >> 1) ^ (l15 & 7)) << 3) + ((s8 & 1) << 2);
#pragma unroll
                    for (int nt = 0; nt < 8; ++nt) {
                        int dh = nt * 16 + l15;
                        half4 vf = *(const half4*)(vb + dh * 64 + off);
                        accO[nt] = __builtin_amdgcn_mfma_f32_16x16x16f16(vf, pb[st], accO[nt], 0, 0, 0);
                    }
                }
        }

        // epilogue: transpose O^T -> O via wave-private LDS, write bf16
        __syncthreads();                              // all waves done reading kS/vS
        ushort* eT = (ushort*)smem + w * 2176;        // [16 q][136 dh-pad]
        float inv = 1.0f / lrow;
#pragma unroll
        for (int nt = 0; nt < 8; ++nt) {
            int dh = nt * 16 + quad * 4;
#pragma unroll
            for (int r = 0; r < 4; ++r)
                eT[l15 * 136 + dh + r] = f2bf(accO[nt][r] * inv);
        }
        for (int idx = lane; idx < 256; idx += 64) {
            int row = idx >> 4, c = idx & 15;
            uint4 v = *(const uint4*)(eT + row * 136 + c * 8);
            *(uint4*)(O + ((size_t)(b * T_) + q0 + w * 16 + row) * D_ + h * DH_ + c * 8) = v;
        }
    }
}

extern "C" void kernel_launch(void* const* d_in, const int* in_sizes, int n_in,
                              void* d_out, int out_size, void* d_ws, size_t ws_size,
                              hipStream_t stream) {
    const float* x  = (const float*)d_in[0];
    const float* Wq = (const float*)d_in[1];
    const float* bq = (const float*)d_in[2];
    const float* Wk = (const float*)d_in[3];
    const float* bk = (const float*)d_in[4];
    const float* Wv = (const float*)d_in[5];
    const float* bv = (const float*)d_in[6];
    const float* Wo = (const float*)d_in[7];
    const float* bo = (const float*)d_in[8];

    char* ws = (char*)d_ws;
    const size_t MB = 1u << 20;
    ushort* xb  = (ushort*)(ws);
    ushort* Wqt = (ushort*)(ws + 32 * MB);
    ushort* Wkt = (ushort*)(ws + 40 * MB);
    ushort* Wvt = (ushort*)(ws + 48 * MB);
    ushort* Wot = (ushort*)(ws + 56 * MB);
    ushort* Qb  = (ushort*)(ws + 64 * MB);
    ushort* Kb  = (ushort*)(ws + 96 * MB);
    ushort* Vtb = (ushort*)(ws + 128 * MB);
    ushort* Ob  = (ushort*)(ws + 160 * MB);

    const int M = B_ * T_;   // 8192
    const float qscale = (float)(0.08838834764831845 * 1.4426950408889634); // 1/sqrt(DH) * log2(e)

    cast_f32_bf16<<<(M * D_) / 1024, 256, 0, stream>>>(x, xb, M * D_);
    dim3 tb(32, 8), tg(D_ / 32, D_ / 32, 4);
    transpose_cast4<<<tg, tb, 0, stream>>>(Wq, Wk, Wv, Wo, Wqt, Wkt, Wvt, Wot);

    gemm_qkv<<<dim3(48, M / 128), 256, 34816, stream>>>(
        xb, Wqt, Wkt, Wvt, bq, bk, bv, Qb, Kb, Vtb, qscale);

    attn_kernel<<<dim3(1024), 256, 0, stream>>>(Qb, Kb, Vtb, Ob);

    gemm_bt_f32<<<dim3(D_ / 128, M / 128), 256, 16384, stream>>>(
        Ob, Wot, bo, (float*)d_out, M, D_, D_);
}